// Round 7
// baseline (44.899 us; speedup 1.0000x reference)
//
#include <hip/hip_runtime.h>

#define B_ 4
#define J_ 8160               // 68*120 cells per batch
#define HF 544
#define WF 960
#define TS 32
#define TXN 30
#define TYN 17
#define NTPB 510              // tiles per batch
#define NTILE (B_*NTPB)       // 2040
#define CAP 1024              // list slots per tile (expected ~130, R1 passed w/ 512)
#define R2COEF 23.0259f       // 2*ln(1e5)

typedef _Float16 half8 __attribute__((ext_vector_type(8)));
typedef float floatx16 __attribute__((ext_vector_type(16)));

// ws layout:
//   float4 cdata[B_*J_]            522,240 B   (mx, my, 1/(2v), conf-masked)
//   int    counts[NTILE]             8,160 B
//   int    lists[NTILE*CAP]      8,355,840 B
#define CDATA_BYTES (B_*J_*16)
#define COUNTS_OFF  CDATA_BYTES
#define LISTS_OFF   (CDATA_BYTES + 8192)         // 16B-aligned

__global__ __launch_bounds__(256) void pif_zero(int* __restrict__ counts) {
    int i = blockIdx.x * 256 + threadIdx.x;
    if (i < NTILE) counts[i] = 0;
}

// Bin + pack: one thread per cell. Writes the drain record and appends the
// cell id to every tile whose pixel range its truncation circle can touch
// (R1-validated superset range: floor((m-r)/32) .. floor((m+r)/32)).
__global__ __launch_bounds__(256) void pif_bin(const float2* __restrict__ mean,
                                               const float* __restrict__ var,
                                               const float* __restrict__ conf,
                                               float4* __restrict__ cdata,
                                               int* __restrict__ counts,
                                               int* __restrict__ lists) {
    int gid = blockIdx.x * 256 + threadIdx.x;
    if (gid >= B_ * J_) return;
    int b = gid / J_;
    int j = gid - b * J_;

    float2 m = mean[gid];
    float v  = var[gid];
    float cf = conf[gid];
    float iv = 1.0f / (2.0f * v);
    cdata[gid] = make_float4(m.x, m.y, iv, cf > 0.1f ? cf : 0.0f);

    if (!(cf > 0.1f)) return;

    float r = sqrtf(R2COEF * v);                 // >= per-cell cut radius
    int tx0 = max(0,       (int)floorf((m.x - r) * (1.0f / TS)));
    int tx1 = min(TXN - 1, (int)floorf((m.x + r) * (1.0f / TS)));
    int ty0 = max(0,       (int)floorf((m.y - r) * (1.0f / TS)));
    int ty1 = min(TYN - 1, (int)floorf((m.y + r) * (1.0f / TS)));

    for (int ty = ty0; ty <= ty1; ++ty) {
        for (int tx = tx0; tx <= tx1; ++tx) {
            int t = (b * TYN + ty) * TXN + tx;
            int idx = atomicAdd(&counts[t], 1);
            if (idx < CAP) lists[t * CAP + idx] = j;
        }
    }
}

// Accum: one block per tile, NO scan — drain the tile's pre-binned list.
// Wave w takes 16-cell chunks w, w+4, w+8, ... into the validated
// v_mfma_f32_32x32x16_f16 rank-16 update (cell -> same k-slot (half,i) in A
// and B; C/D row=(r&3)+8*(r>>2)+4*half). LDS-reduce the 4 partial tiles.
__global__ __launch_bounds__(256, 8) void pif_accum(const float4* __restrict__ cdata,
                                                    const int* __restrict__ counts,
                                                    const int* __restrict__ lists,
                                                    float* __restrict__ out) {
    __shared__ float red[4][32][32];
    int wid  = threadIdx.x >> 6;
    int lane = threadIdx.x & 63;
    int tile = blockIdx.x;                        // 0..509
    int b    = blockIdx.y;

    int ty = tile / TXN;
    int tx = tile - ty * TXN;
    int t  = b * NTPB + tile;

    int c = counts[t];
    if (c > CAP) c = CAP;
    const int*    list = lists + t * CAP;
    const float4* cb   = cdata + (size_t)b * J_;

    int   lx = lane & 31, half = lane >> 5;
    float xf = (float)(tx * TS + lx);
    float yf = (float)(ty * TS + lx);

    floatx16 acc = {};
    int nch = (c + 15) >> 4;

    for (int ch = wid; ch < nch; ch += 4) {
        int base = ch * 16;
        half8 af, bf;
        #pragma unroll
        for (int i = 0; i < 8; ++i) {
            int ci = base + 8 * half + i;
            // broadcast loads (uniform per half-wave): list entry, then record
            float4 cd = (ci < c) ? cb[list[ci]] : make_float4(0.f, 0.f, 1.f, 0.f);
            float dy = yf - cd.y;
            float dx = xf - cd.x;
            af[i] = (_Float16)__expf(-dy * dy * cd.z);
            bf[i] = (_Float16)(cd.w * __expf(-dx * dx * cd.z));  // w=0 -> no contribution
        }
        acc = __builtin_amdgcn_mfma_f32_32x32x16_f16(af, bf, acc, 0, 0, 0);
    }

    __syncthreads();
    #pragma unroll
    for (int r = 0; r < 16; ++r) {
        int row = (r & 3) + 8 * (r >> 2) + 4 * half;
        red[wid][row][lx] = acc[r];               // 2-way bank alias: free
    }
    __syncthreads();

    int th = threadIdx.x;
    #pragma unroll
    for (int k = 0; k < 4; ++k) {
        int p   = th + 256 * k;
        int row = p >> 5, col = p & 31;
        float s = red[0][row][col] + red[1][row][col]
                + red[2][row][col] + red[3][row][col];
        out[((size_t)(b * HF + ty * TS + row)) * WF + (tx * TS + col)] = s;
    }
}

extern "C" void kernel_launch(void* const* d_in, const int* in_sizes, int n_in,
                              void* d_out, int out_size, void* d_ws, size_t ws_size,
                              hipStream_t stream) {
    const float2* mean = (const float2*)d_in[0];
    const float*  var  = (const float*)d_in[1];
    const float*  conf = (const float*)d_in[2];
    float* out = (float*)d_out;

    char* ws = (char*)d_ws;
    float4* cdata = (float4*)ws;
    int* counts   = (int*)(ws + COUNTS_OFF);
    int* lists    = (int*)(ws + LISTS_OFF);

    pif_zero<<<(NTILE + 255) / 256, 256, 0, stream>>>(counts);
    pif_bin<<<(B_ * J_ + 255) / 256, 256, 0, stream>>>(mean, var, conf,
                                                       cdata, counts, lists);
    pif_accum<<<dim3(NTPB, B_), 256, 0, stream>>>(cdata, counts, lists, out);
}

// Round 8
// 30.060 us; speedup vs baseline: 1.4936x; 1.4936x over previous
//
#include <hip/hip_runtime.h>

#define B_ 4
#define J_ 8160               // 68*120 cells per batch
#define HF 544
#define WF 960
#define TS 32
#define TXN 30
#define TYN 17
#define NTPB 510              // tiles per batch
#define NTILE (B_*NTPB)       // 2040
#define CAP 512               // list slots per tile (expected ~130)
#define CSTRIDE 16            // counters padded to one 64B line each
#define R2COEF 23.0259f       // 2*ln(1e5)

typedef _Float16 half8 __attribute__((ext_vector_type(8)));
typedef float floatx16 __attribute__((ext_vector_type(16)));

// ws layout (16B-aligned sections):
//   float4 cdata[B_*J_]               522,240 B  (mx, my, 1/(2v), conf-masked)
//   uint   binfo[B_*J_]               130,560 B  (tx0|ty0<<5|nx<<10|ny<<13|valid<<16)
//   int    counts[NTILE*CSTRIDE]      130,560 B
//   int    lists[NTILE*CAP]         4,177,920 B
#define BINFO_OFF  (B_*J_*16)
#define COUNTS_OFF (BINFO_OFF + B_*J_*4)
#define LISTS_OFF  (COUNTS_OFF + NTILE*CSTRIDE*4)

// K1: pack drain records, build bin descriptors, zero padded counters.
__global__ __launch_bounds__(256) void pif_prep(const float2* __restrict__ mean,
                                                const float* __restrict__ var,
                                                const float* __restrict__ conf,
                                                float4* __restrict__ cdata,
                                                unsigned* __restrict__ binfo,
                                                int* __restrict__ counts) {
    int gid = blockIdx.x * 256 + threadIdx.x;
    if (gid < NTILE) counts[gid * CSTRIDE] = 0;
    if (gid >= B_ * J_) return;

    float2 m = mean[gid];
    float v  = var[gid];
    float cf = conf[gid];
    bool act = cf > 0.1f;
    cdata[gid] = make_float4(m.x, m.y, 1.0f / (2.0f * v), act ? cf : 0.0f);

    unsigned bi = 0;
    if (act) {
        float r = sqrtf(R2COEF * v);              // <= 38.4 px -> footprint <= 4x4 tiles
        int tx0 = max(0,       (int)floorf((m.x - r) * (1.0f / TS)));
        int tx1 = min(TXN - 1, (int)floorf((m.x + r) * (1.0f / TS)));
        int ty0 = max(0,       (int)floorf((m.y - r) * (1.0f / TS)));
        int ty1 = min(TYN - 1, (int)floorf((m.y + r) * (1.0f / TS)));
        int nx = tx1 - tx0 + 1, ny = ty1 - ty0 + 1;   // 1..4
        bi = (unsigned)tx0 | ((unsigned)ty0 << 5) | ((unsigned)nx << 10)
           | ((unsigned)ny << 13) | (1u << 16);
    }
    binfo[gid] = bi;
}

// K2: scatter, one thread per (cell, slot) pair -- 16 slots cover the 4x4
// max footprint. Every thread does at most ONE independent atomic+store:
// no serial atomic chains (R7's failure mode).
__global__ __launch_bounds__(256) void pif_scatter(const unsigned* __restrict__ binfo,
                                                   int* __restrict__ counts,
                                                   int* __restrict__ lists) {
    int tid  = blockIdx.x * 256 + threadIdx.x;     // 0 .. B_*J_*16-1
    int cell = tid >> 4;                           // 16 lanes share a cell -> L1 broadcast
    int s    = tid & 15;
    unsigned bi = binfo[cell];
    if (!(bi >> 16)) return;
    int sx = s & 3, sy = s >> 2;
    int nx = (bi >> 10) & 7, ny = (bi >> 13) & 7;
    if (sx >= nx || sy >= ny) return;
    int tx0 = bi & 31, ty0 = (bi >> 5) & 31;
    int b = cell / J_;
    int j = cell - b * J_;
    int t = (b * TYN + ty0 + sy) * TXN + (tx0 + sx);
    int idx = atomicAdd(&counts[t * CSTRIDE], 1);
    if (idx < CAP) lists[t * CAP + idx] = j;
}

// K3: accum, NO scan. Stage the tile's list into LDS coalesced, then the
// R3-R6-validated v_mfma_f32_32x32x16_f16 drain (cell -> same k-slot (half,i)
// in A and B; C/D row=(r&3)+8*(r>>2)+4*half), LDS-reduce 4 partials, store.
__global__ __launch_bounds__(256, 8) void pif_accum(const float4* __restrict__ cdata,
                                                    const int* __restrict__ counts,
                                                    const int* __restrict__ lists,
                                                    float* __restrict__ out) {
    __shared__ float red[4][32][32];               // first 2KB alias as list staging
    int* ql = (int*)&red[0][0][0];

    int wid  = threadIdx.x >> 6;
    int lane = threadIdx.x & 63;
    int tile = blockIdx.x;                         // 0..509
    int b    = blockIdx.y;

    int ty = tile / TXN;
    int tx = tile - ty * TXN;
    int t  = b * NTPB + tile;

    int c = counts[t * CSTRIDE];
    if (c > CAP) c = CAP;
    const int*    list = lists + t * CAP;
    const float4* cb   = cdata + (size_t)b * J_;

    for (int i = threadIdx.x; i < c; i += 256) ql[i] = list[i];
    __syncthreads();

    int   lx = lane & 31, half = lane >> 5;
    float xf = (float)(tx * TS + lx);
    float yf = (float)(ty * TS + lx);

    floatx16 acc = {};
    int nch = (c + 15) >> 4;

    for (int ch = wid; ch < nch; ch += 4) {
        int base = ch * 16;
        half8 af, bf;
        #pragma unroll
        for (int i = 0; i < 8; ++i) {
            int ci = base + 8 * half + i;
            // ql read: uniform per half-wave -> LDS broadcast; cb: L2 broadcast
            float4 cd = (ci < c) ? cb[ql[ci]] : make_float4(0.f, 0.f, 1.f, 0.f);
            float dy = yf - cd.y;
            float dx = xf - cd.x;
            af[i] = (_Float16)__expf(-dy * dy * cd.z);
            bf[i] = (_Float16)(cd.w * __expf(-dx * dx * cd.z));  // w=0 -> no contribution
        }
        acc = __builtin_amdgcn_mfma_f32_32x32x16_f16(af, bf, acc, 0, 0, 0);
    }

    __syncthreads();                               // ql dead; red reuse safe
    #pragma unroll
    for (int r = 0; r < 16; ++r) {
        int row = (r & 3) + 8 * (r >> 2) + 4 * half;
        red[wid][row][lx] = acc[r];                // 2-way bank alias: free
    }
    __syncthreads();

    int th = threadIdx.x;
    #pragma unroll
    for (int k = 0; k < 4; ++k) {
        int p   = th + 256 * k;
        int row = p >> 5, col = p & 31;
        float s = red[0][row][col] + red[1][row][col]
                + red[2][row][col] + red[3][row][col];
        out[((size_t)(b * HF + ty * TS + row)) * WF + (tx * TS + col)] = s;
    }
}

extern "C" void kernel_launch(void* const* d_in, const int* in_sizes, int n_in,
                              void* d_out, int out_size, void* d_ws, size_t ws_size,
                              hipStream_t stream) {
    const float2* mean = (const float2*)d_in[0];
    const float*  var  = (const float*)d_in[1];
    const float*  conf = (const float*)d_in[2];
    float* out = (float*)d_out;

    char* ws = (char*)d_ws;
    float4*   cdata  = (float4*)ws;
    unsigned* binfo  = (unsigned*)(ws + BINFO_OFF);
    int*      counts = (int*)(ws + COUNTS_OFF);
    int*      lists  = (int*)(ws + LISTS_OFF);

    pif_prep<<<(B_ * J_ + 255) / 256, 256, 0, stream>>>(mean, var, conf,
                                                        cdata, binfo, counts);
    pif_scatter<<<(B_ * J_ * 16) / 256, 256, 0, stream>>>(binfo, counts, lists);
    pif_accum<<<dim3(NTPB, B_), 256, 0, stream>>>(cdata, counts, lists, out);
}

// Round 9
// 27.369 us; speedup vs baseline: 1.6405x; 1.0984x over previous
//
#include <hip/hip_runtime.h>

#define B_ 4
#define J_ 8160               // 68*120 cells per batch
#define HF 544
#define WF 960
#define TS 32
#define TXN 30
#define TYN 17
#define NTPB 510              // tiles per batch; grid = 2040 blocks = 8/CU
#define RMAX2 1474.0f         // 23.0259 * var_max(=64): fixed conservative cut

typedef _Float16 half8 __attribute__((ext_vector_type(8)));
typedef float floatx16 __attribute__((ext_vector_type(16)));

// SINGLE dispatch (the ~7us/graph-node overhead model from R4-R8 says two
// dispatches cost ~14us before any kernel runs). One block per 32x32 tile,
// 4 waves; wave w scans raw cells [w*2048,(w+1)*2048): 2 cells/lane/iter
// (float4 over mean + float2 over conf; var NOT read in the scan - fixed
// radius), circle-vs-clamped-point test, ballot-compact into per-wave LDS
// queue, drain 16 at a time into v_mfma_f32_32x32x16_f16 (layout validated
// R3-R8: cell -> same k-slot (half,i) in A and B; C/D
// row=(r&3)+8*(r>>2)+4*half). LDS-reduce 4 partials, store.
__global__ __launch_bounds__(256, 8) void pif_one(const float2* __restrict__ mean,
                                                  const float*  __restrict__ var,
                                                  const float*  __restrict__ conf,
                                                  float* __restrict__ out) {
    __shared__ float red[4][32][32];   // per-wave queue first, partial tiles later
    int wid  = threadIdx.x >> 6;
    int lane = threadIdx.x & 63;
    int tile = blockIdx.x;             // 0..509
    int b    = blockIdx.y;

    int ty = tile / TXN;
    int tx = tile - ty * TXN;

    const float2* mb = mean + (size_t)b * J_;
    const float*  vb = var  + (size_t)b * J_;
    const float*  cb = conf + (size_t)b * J_;
    const float4* mb4 = (const float4*)mb;     // 2 cells per element
    const float2* cb2 = (const float2*)cb;

    int* q  = (int*)&red[wid][0][0];   // 1024 ints per wave
    int  qn = 0;

    float x0 = (float)(tx * TS), y0 = (float)(ty * TS);
    float x1 = x0 + 31.f,        y1 = y0 + 31.f;
    int   lx = lane & 31, half = lane >> 5;
    float xf = x0 + (float)lx;
    float yf = y0 + (float)lx;
    const unsigned long long below = (1ull << lane) - 1ull;

    floatx16 acc = {};

    auto drain16 = [&](const int* qq) {
        half8 af, bf;
        #pragma unroll
        for (int i = 0; i < 8; ++i) {
            int cidx = qq[8 * half + i];       // LDS broadcast per half-wave
            float2 m  = mb[cidx];              // broadcast global loads (L2)
            float  v  = vb[cidx];
            float  cf = cb[cidx];
            float iv = __builtin_amdgcn_rcpf(2.0f * v);
            float dy = yf - m.y;
            float dx = xf - m.x;
            af[i] = (_Float16)__expf(-dy * dy * iv);
            bf[i] = (_Float16)(cf * __expf(-dx * dx * iv));
        }
        acc = __builtin_amdgcn_mfma_f32_32x32x16_f16(af, bf, acc, 0, 0, 0);
    };

    int jbase = wid * 2048;                    // this wave's padded slice
    for (int s = 0; s < 16; ++s) {
        int j0 = jbase + s * 128 + 2 * lane;   // even
        bool valid = j0 < J_;                  // j0<J_ (even) => j0+1<J_ too
        int jl = valid ? j0 : 0;               // safe aligned load base

        float4 mm = mb4[jl >> 1];              // means of cells jl, jl+1
        float2 cc = cb2[jl >> 1];              // their confidences

        float cx0 = fminf(fmaxf(mm.x, x0), x1);
        float cy0 = fminf(fmaxf(mm.y, y0), y1);
        float cx1 = fminf(fmaxf(mm.z, x0), x1);
        float cy1 = fminf(fmaxf(mm.w, y0), y1);
        float dx0 = mm.x - cx0, dy0 = mm.y - cy0;
        float dx1 = mm.z - cx1, dy1 = mm.w - cy1;
        bool p0 = valid & (cc.x > 0.1f) & (dx0 * dx0 + dy0 * dy0 <= RMAX2);
        bool p1 = valid & (cc.y > 0.1f) & (dx1 * dx1 + dy1 * dy1 <= RMAX2);

        unsigned long long m0 = __ballot(p0);
        if (p0) q[qn + __popcll(m0 & below)] = j0;
        qn += __popcll(m0);
        unsigned long long m1 = __ballot(p1);
        if (p1) q[qn + __popcll(m1 & below)] = j0 + 1;
        qn += __popcll(m1);                    // grows <=128/iter

        if (__builtin_expect(qn >= 896, 0)) {  // cold: adversarial data only
            while (qn >= 16) { qn -= 16; drain16(q + qn); }
        }
    }

    while (qn >= 16) { qn -= 16; drain16(q + qn); }
    if (qn > 0) {                              // padded tail chunk
        half8 af, bf;
        #pragma unroll
        for (int i = 0; i < 8; ++i) {
            int ci = 8 * half + i;
            float2 m; float v, cf;
            if (ci < qn) { int cidx = q[ci]; m = mb[cidx]; v = vb[cidx]; cf = cb[cidx]; }
            else         { m = make_float2(0.f, 0.f); v = 1.f; cf = 0.f; }
            float iv = __builtin_amdgcn_rcpf(2.0f * v);
            float dy = yf - m.y;
            float dx = xf - m.x;
            af[i] = (_Float16)__expf(-dy * dy * iv);
            bf[i] = (_Float16)(cf * __expf(-dx * dx * iv));   // cf=0 -> no contribution
        }
        acc = __builtin_amdgcn_mfma_f32_32x32x16_f16(af, bf, acc, 0, 0, 0);
    }

    // queue regions dead from here; reuse red[] for the 4 partial tiles
    __syncthreads();
    #pragma unroll
    for (int r = 0; r < 16; ++r) {
        int row = (r & 3) + 8 * (r >> 2) + 4 * half;
        red[wid][row][lx] = acc[r];            // 2-way bank alias: free
    }
    __syncthreads();

    int th = threadIdx.x;
    #pragma unroll
    for (int k = 0; k < 4; ++k) {
        int p   = th + 256 * k;
        int row = p >> 5, col = p & 31;
        float s = red[0][row][col] + red[1][row][col]
                + red[2][row][col] + red[3][row][col];
        out[((size_t)(b * HF + ty * TS + row)) * WF + (tx * TS + col)] = s;
    }
}

extern "C" void kernel_launch(void* const* d_in, const int* in_sizes, int n_in,
                              void* d_out, int out_size, void* d_ws, size_t ws_size,
                              hipStream_t stream) {
    const float2* mean = (const float2*)d_in[0];
    const float*  var  = (const float*)d_in[1];
    const float*  conf = (const float*)d_in[2];
    float* out = (float*)d_out;
    (void)d_ws; (void)ws_size;

    pif_one<<<dim3(NTPB, B_), 256, 0, stream>>>(mean, var, conf, out);
}

// Round 10
// 24.514 us; speedup vs baseline: 1.8316x; 1.1165x over previous
//
#include <hip/hip_runtime.h>

#define B_ 4
#define J_ 8160               // 68*120 cells per batch
#define HF 544
#define WF 960
#define TS 32
#define TXN 30
#define TYN 17
#define NTPB 510              // tiles per batch; grid = 2040 blocks = 8/CU
#define R2COEF 23.0259f       // 2*ln(1e5): exact per-cell truncation radius^2 / var

typedef _Float16 half8 __attribute__((ext_vector_type(8)));
typedef float floatx16 __attribute__((ext_vector_type(16)));

// SINGLE dispatch (R1-R9 fit: ~7us per graph node). One block per 32x32 tile,
// 4 waves; wave w scans raw cells [w*2048,(w+1)*2048), 2 cells/lane/iter
// (float4 mean + float2 var + float2 conf = 16B/cell), exact-radius test,
// ballot-compacts COMPLETE records (mx,my,1/(2v),cf) into a per-wave LDS
// queue -- so the drain is global-memory-free (R9's 3-gather drain was the
// suspected ~8us sin under the 64-VGPR cap). Drain 16 cells at a time into
// v_mfma_f32_32x32x16_f16 (layout validated R3-R9: cell -> same k-slot
// (half,i) in A and B; C/D row=(r&3)+8*(r>>2)+4*half). LDS-reduce 4 partial
// tiles, store.
__global__ __launch_bounds__(256, 8) void pif_one(const float2* __restrict__ mean,
                                                  const float*  __restrict__ var,
                                                  const float*  __restrict__ conf,
                                                  float* __restrict__ out) {
    __shared__ float4 qbuf[4][256];    // per-wave survivor queues; re-used as red[]
    int wid  = threadIdx.x >> 6;
    int lane = threadIdx.x & 63;
    int tile = blockIdx.x;             // 0..509
    int b    = blockIdx.y;

    int ty = tile / TXN;
    int tx = tile - ty * TXN;

    const float4* mb4 = (const float4*)(mean + (size_t)b * J_);  // 2 cells/elt
    const float2* vb2 = (const float2*)(var  + (size_t)b * J_);
    const float2* cb2 = (const float2*)(conf + (size_t)b * J_);

    float4* q = qbuf[wid];
    int qn = 0;

    float x0 = (float)(tx * TS), y0 = (float)(ty * TS);
    float x1 = x0 + 31.f,        y1 = y0 + 31.f;
    int   lx = lane & 31, half = lane >> 5;
    float xf = x0 + (float)lx;
    float yf = y0 + (float)lx;
    const unsigned long long below = (1ull << lane) - 1ull;

    floatx16 acc = {};

    auto drain16 = [&](int base) {     // consumes q[base..base+15], LDS-only
        half8 af, bf;
        #pragma unroll
        for (int i = 0; i < 8; ++i) {
            float4 e = q[base + 8 * half + i];   // uniform per half-wave: broadcast
            float dy = yf - e.y;
            float dx = xf - e.x;
            af[i] = (_Float16)__expf(-dy * dy * e.z);
            bf[i] = (_Float16)(e.w * __expf(-dx * dx * e.z));  // w=0 -> no contribution
        }
        acc = __builtin_amdgcn_mfma_f32_32x32x16_f16(af, bf, acc, 0, 0, 0);
    };

    int jbase = wid * 2048;                    // this wave's padded slice
    for (int s = 0; s < 16; ++s) {
        int j0 = jbase + s * 128 + 2 * lane;   // even
        bool valid = j0 < J_;                  // j0 even: valid => j0+1 valid too
        int  jh = (valid ? j0 : 0) >> 1;       // safe aligned load index

        float4 mm = mb4[jh];                   // means of the 2 cells
        float2 vv = vb2[jh];                   // their variances
        float2 cc = cb2[jh];                   // their confidences

        float cx0 = fminf(fmaxf(mm.x, x0), x1);
        float cy0 = fminf(fmaxf(mm.y, y0), y1);
        float cx1 = fminf(fmaxf(mm.z, x0), x1);
        float cy1 = fminf(fmaxf(mm.w, y0), y1);
        float dx0 = mm.x - cx0, dy0 = mm.y - cy0;
        float dx1 = mm.z - cx1, dy1 = mm.w - cy1;
        bool p0 = valid & (cc.x > 0.1f) & (dx0 * dx0 + dy0 * dy0 <= R2COEF * vv.x);
        bool p1 = valid & (cc.y > 0.1f) & (dx1 * dx1 + dy1 * dy1 <= R2COEF * vv.y);

        // compact cell 0 records
        unsigned long long m0 = __ballot(p0);
        if (p0) q[qn + __popcll(m0 & below)] =
            make_float4(mm.x, mm.y, __builtin_amdgcn_rcpf(2.0f * vv.x), cc.x);
        qn += __popcll(m0);                    // writes at <= qn+63 <= 206 < 256
        if (__builtin_expect(qn >= 144, 0)) {  // cold: keeps qn <= 143 post-iter
            while (qn >= 16) { qn -= 16; drain16(qn); }
        }
        // compact cell 1 records
        unsigned long long m1 = __ballot(p1);
        if (p1) q[qn + __popcll(m1 & below)] =
            make_float4(mm.z, mm.w, __builtin_amdgcn_rcpf(2.0f * vv.y), cc.y);
        qn += __popcll(m1);
        if (__builtin_expect(qn >= 144, 0)) {
            while (qn >= 16) { qn -= 16; drain16(qn); }
        }
    }

    while (qn >= 16) { qn -= 16; drain16(qn); }
    if (qn > 0) {                              // pad tail to a full chunk
        if (lane >= qn && lane < 16)
            q[lane] = make_float4(0.f, 0.f, 0.f, 0.f);   // cf=0: inert
        drain16(0);                            // wave-local LDS: no barrier needed
    }

    // queue regions dead from here; alias qbuf as the 4 partial 32x32 tiles
    __syncthreads();
    float (*red)[32][32] = (float (*)[32][32])qbuf;      // 16 KB alias
    #pragma unroll
    for (int r = 0; r < 16; ++r) {
        int row = (r & 3) + 8 * (r >> 2) + 4 * half;
        red[wid][row][lx] = acc[r];            // 2-way bank alias: free
    }
    __syncthreads();

    int th = threadIdx.x;
    #pragma unroll
    for (int k = 0; k < 4; ++k) {
        int p   = th + 256 * k;
        int row = p >> 5, col = p & 31;
        float s = red[0][row][col] + red[1][row][col]
                + red[2][row][col] + red[3][row][col];
        out[((size_t)(b * HF + ty * TS + row)) * WF + (tx * TS + col)] = s;
    }
}

extern "C" void kernel_launch(void* const* d_in, const int* in_sizes, int n_in,
                              void* d_out, int out_size, void* d_ws, size_t ws_size,
                              hipStream_t stream) {
    const float2* mean = (const float2*)d_in[0];
    const float*  var  = (const float*)d_in[1];
    const float*  conf = (const float*)d_in[2];
    float* out = (float*)d_out;
    (void)d_ws; (void)ws_size;

    pif_one<<<dim3(NTPB, B_), 256, 0, stream>>>(mean, var, conf, out);
}